// Round 2
// baseline (8926.993 us; speedup 1.0000x reference)
//
#include <hip/hip_runtime.h>

#define HID 128

// ---------------- degree ----------------
__global__ void deg_kernel(const int* __restrict__ dst, float* __restrict__ deg, int n_edges) {
    int e = blockIdx.x * blockDim.x + threadIdx.x;
    if (e < n_edges) atomicAdd(&deg[dst[e]], 1.0f);
}

__global__ void inv_deg_kernel(const float* __restrict__ deg, float* __restrict__ invd, int n) {
    int i = blockIdx.x * blockDim.x + threadIdx.x;
    if (i < n) invd[i] = 1.0f / fmaxf(deg[i], 1.0f);
}

// ---------------- edge scatter-add: agg[dst] += h[src] ----------------
// thread = (edge, 4-float chunk); 32 threads per edge cover 128 feats.
__global__ void scatter_kernel(const float* __restrict__ h, const int* __restrict__ src,
                               const int* __restrict__ dst, float* __restrict__ agg, int n_edges) {
    long long gid = (long long)blockIdx.x * blockDim.x + threadIdx.x;
    int e = (int)(gid >> 5);
    if (e >= n_edges) return;
    int q = ((int)gid & 31) * 4;
    int s = src[e], d = dst[e];
    float4 v = *reinterpret_cast<const float4*>(h + (size_t)s * HID + q);
    float* a = agg + (size_t)d * HID + q;
    atomicAdd(a + 0, v.x);
    atomicAdd(a + 1, v.y);
    atomicAdd(a + 2, v.z);
    atomicAdd(a + 3, v.w);
}

// ---------------- fused dual-GEMM + epilogue ----------------
// out[i][:] = A[i]@Ws + (Agg[i]*invd[i])@Wn + bias ; if HAS_MASK: where(mask, ., gh[g2[i]]) then relu
// BM=64 rows/block, 256 threads, each thread 4 rows x 8 cols. K fixed at 128 per pass, 2 passes.
template<int NOUT, bool HAS_MASK>
__global__ __launch_bounds__(256) void gemm_fused(
    const float* __restrict__ A, const float* __restrict__ Agg,
    const float* __restrict__ invd,
    const float* __restrict__ Ws, const float* __restrict__ Wn,
    const float* __restrict__ bias,
    const float* __restrict__ gh, const int* __restrict__ g2,
    const int* __restrict__ mask,
    float* __restrict__ out, int n_rows)
{
    __shared__ float sA[64][33];
    __shared__ float sB[32][128];

    const int tid = threadIdx.x;
    const int tx  = tid & 15;   // col group: cols tx*8 .. tx*8+7
    const int tyy = tid >> 4;   // row group: rows tyy*4 .. tyy*4+3
    const int r0  = blockIdx.x * 64;

    float acc[4][8];
#pragma unroll
    for (int r = 0; r < 4; ++r)
#pragma unroll
        for (int c = 0; c < 8; ++c) acc[r][c] = 0.0f;

    for (int pass = 0; pass < 2; ++pass) {
        const float* __restrict__ Asrc = pass ? Agg : A;
        const float* __restrict__ W    = pass ? Wn  : Ws;
        for (int k0 = 0; k0 < 128; k0 += 32) {
            __syncthreads();
            // load A tile: 64 x 32 floats
#pragma unroll
            for (int i = 0; i < 2; ++i) {
                int fid = tid + i * 256;
                int row = fid >> 3;
                int c4  = (fid & 7) * 4;
                int gr  = r0 + row;
                float4 v = make_float4(0.f, 0.f, 0.f, 0.f);
                if (gr < n_rows) {
                    v = *reinterpret_cast<const float4*>(Asrc + (size_t)gr * HID + k0 + c4);
                    if (pass) { float s = invd[gr]; v.x *= s; v.y *= s; v.z *= s; v.w *= s; }
                }
                sA[row][c4 + 0] = v.x;
                sA[row][c4 + 1] = v.y;
                sA[row][c4 + 2] = v.z;
                sA[row][c4 + 3] = v.w;
            }
            // load B tile: 32 x NOUT (zero-padded to 128 cols)
#pragma unroll
            for (int i = 0; i < 4; ++i) {
                int fid = tid + i * 256;
                int row = fid >> 5;
                int col = (fid & 31) * 4;
                float4 v = make_float4(0.f, 0.f, 0.f, 0.f);
                if (col < NOUT)
                    v = *reinterpret_cast<const float4*>(W + (size_t)(k0 + row) * NOUT + col);
                *reinterpret_cast<float4*>(&sB[row][col]) = v;
            }
            __syncthreads();
#pragma unroll
            for (int k = 0; k < 32; ++k) {
                float a0 = sA[tyy * 4 + 0][k];
                float a1 = sA[tyy * 4 + 1][k];
                float a2 = sA[tyy * 4 + 2][k];
                float a3 = sA[tyy * 4 + 3][k];
                float4 blo = *reinterpret_cast<const float4*>(&sB[k][tx * 8]);
                float4 bhi = *reinterpret_cast<const float4*>(&sB[k][tx * 8 + 4]);
                acc[0][0] += a0 * blo.x; acc[0][1] += a0 * blo.y; acc[0][2] += a0 * blo.z; acc[0][3] += a0 * blo.w;
                acc[0][4] += a0 * bhi.x; acc[0][5] += a0 * bhi.y; acc[0][6] += a0 * bhi.z; acc[0][7] += a0 * bhi.w;
                acc[1][0] += a1 * blo.x; acc[1][1] += a1 * blo.y; acc[1][2] += a1 * blo.z; acc[1][3] += a1 * blo.w;
                acc[1][4] += a1 * bhi.x; acc[1][5] += a1 * bhi.y; acc[1][6] += a1 * bhi.z; acc[1][7] += a1 * bhi.w;
                acc[2][0] += a2 * blo.x; acc[2][1] += a2 * blo.y; acc[2][2] += a2 * blo.z; acc[2][3] += a2 * blo.w;
                acc[2][4] += a2 * bhi.x; acc[2][5] += a2 * bhi.y; acc[2][6] += a2 * bhi.z; acc[2][7] += a2 * bhi.w;
                acc[3][0] += a3 * blo.x; acc[3][1] += a3 * blo.y; acc[3][2] += a3 * blo.z; acc[3][3] += a3 * blo.w;
                acc[3][4] += a3 * bhi.x; acc[3][5] += a3 * bhi.y; acc[3][6] += a3 * bhi.z; acc[3][7] += a3 * bhi.w;
            }
        }
    }

    // epilogue
#pragma unroll
    for (int rr = 0; rr < 4; ++rr) {
        int gr = r0 + tyy * 4 + rr;
        if (gr >= n_rows) continue;
        bool mk = true;
        const float* grow = nullptr;
        if (HAS_MASK) {
            mk = mask[gr] != 0;
            if (!mk) grow = gh + (size_t)g2[gr] * HID;
        }
#pragma unroll
        for (int h4 = 0; h4 < 2; ++h4) {
            int col = tx * 8 + h4 * 4;
            if (col >= NOUT) continue;
            float4 y;
            y.x = acc[rr][h4 * 4 + 0] + bias[col + 0];
            y.y = acc[rr][h4 * 4 + 1] + bias[col + 1];
            y.z = acc[rr][h4 * 4 + 2] + bias[col + 2];
            y.w = acc[rr][h4 * 4 + 3] + bias[col + 3];
            if (HAS_MASK) {
                if (!mk) {
                    y.x = grow[col + 0]; y.y = grow[col + 1];
                    y.z = grow[col + 2]; y.w = grow[col + 3];
                }
                y.x = fmaxf(y.x, 0.f); y.y = fmaxf(y.y, 0.f);
                y.z = fmaxf(y.z, 0.f); y.w = fmaxf(y.w, 0.f);
            }
            *reinterpret_cast<float4*>(out + (size_t)gr * NOUT + col) = y;
        }
    }
}

extern "C" void kernel_launch(void* const* d_in, const int* in_sizes, int n_in,
                              void* d_out, int out_size, void* d_ws, size_t ws_size,
                              hipStream_t stream) {
    const float* feat = (const float*)d_in[0];
    const float* gh   = (const float*)d_in[1];
    const float* gh2  = (const float*)d_in[2];
    const float* W1s  = (const float*)d_in[3];
    const float* W1n  = (const float*)d_in[4];
    const float* b1   = (const float*)d_in[5];
    const float* W2s  = (const float*)d_in[6];
    const float* W2n  = (const float*)d_in[7];
    const float* b2   = (const float*)d_in[8];
    const float* W3s  = (const float*)d_in[9];
    const float* W3n  = (const float*)d_in[10];
    const float* b3   = (const float*)d_in[11];
    const int* esrc   = (const int*)d_in[12];
    const int* edst   = (const int*)d_in[13];
    const int* g2     = (const int*)d_in[14];
    const int* mask   = (const int*)d_in[15];   // bool delivered as int32 by the harness

    const int n_edges = in_sizes[12];
    const int n_nodes = in_sizes[14];
    float* out = (float*)d_out;

    float* ws   = (float*)d_ws;
    float* deg  = ws;
    float* invd = deg + n_nodes;
    float* agg  = invd + n_nodes;
    float* h1   = agg + (size_t)n_nodes * HID;
    float* h2   = h1  + (size_t)n_nodes * HID;

    const size_t aggBytes = (size_t)n_nodes * HID * sizeof(float);
    const int sblocks = (int)(((long long)n_edges * 32 + 255) / 256);
    const int gblocks = (n_nodes + 63) / 64;

    // degree (shared by all layers)
    hipMemsetAsync(deg, 0, (size_t)n_nodes * sizeof(float), stream);
    deg_kernel<<<(n_edges + 255) / 256, 256, 0, stream>>>(edst, deg, n_edges);
    inv_deg_kernel<<<(n_nodes + 255) / 256, 256, 0, stream>>>(deg, invd, n_nodes);

    // layer 1
    hipMemsetAsync(agg, 0, aggBytes, stream);
    scatter_kernel<<<sblocks, 256, 0, stream>>>(feat, esrc, edst, agg, n_edges);
    gemm_fused<128, true><<<gblocks, 256, 0, stream>>>(feat, agg, invd, W1s, W1n, b1, gh, g2, mask, h1, n_nodes);

    // layer 2
    hipMemsetAsync(agg, 0, aggBytes, stream);
    scatter_kernel<<<sblocks, 256, 0, stream>>>(h1, esrc, edst, agg, n_edges);
    gemm_fused<128, true><<<gblocks, 256, 0, stream>>>(h1, agg, invd, W2s, W2n, b2, gh2, g2, mask, h2, n_nodes);

    // layer 3 (no mask/relu, 40 output cols)
    hipMemsetAsync(agg, 0, aggBytes, stream);
    scatter_kernel<<<sblocks, 256, 0, stream>>>(h2, esrc, edst, agg, n_edges);
    gemm_fused<40, false><<<gblocks, 256, 0, stream>>>(h2, agg, invd, W3s, W3n, b3, nullptr, nullptr, nullptr, out, n_nodes);
}

// Round 3
// 1271.396 us; speedup vs baseline: 7.0214x; 7.0214x over previous
//
#include <hip/hip_runtime.h>

#define HID 128

// ---------------- CSR build ----------------
__global__ void deg_count_kernel(const int* __restrict__ dst, int* __restrict__ deg, int n_edges) {
    int e = blockIdx.x * blockDim.x + threadIdx.x;
    if (e < n_edges) atomicAdd(&deg[dst[e]], 1);
}

#define SCAN_BS 256
#define SCAN_ELEMS 1024  // 4 per thread

__global__ void scan1_kernel(const int* __restrict__ deg, int* __restrict__ excl,
                             int* __restrict__ blockSums, int n) {
    __shared__ int s[SCAN_BS];
    int base = blockIdx.x * SCAN_ELEMS + threadIdx.x * 4;
    int v[4]; int t = 0;
#pragma unroll
    for (int i = 0; i < 4; ++i) { int idx = base + i; v[i] = (idx < n) ? deg[idx] : 0; t += v[i]; }
    s[threadIdx.x] = t;
    __syncthreads();
    for (int off = 1; off < SCAN_BS; off <<= 1) {
        int x = (threadIdx.x >= off) ? s[threadIdx.x - off] : 0;
        __syncthreads();
        s[threadIdx.x] += x;
        __syncthreads();
    }
    int run = s[threadIdx.x] - t;   // exclusive offset for this thread within block
#pragma unroll
    for (int i = 0; i < 4; ++i) { int idx = base + i; if (idx < n) excl[idx] = run; run += v[i]; }
    if (threadIdx.x == SCAN_BS - 1) blockSums[blockIdx.x] = s[SCAN_BS - 1];
}

__global__ void scan2_kernel(int* __restrict__ blockSums, int nb) {
    if (threadIdx.x == 0 && blockIdx.x == 0) {
        int run = 0;
        for (int i = 0; i < nb; ++i) { int v = blockSums[i]; blockSums[i] = run; run += v; }
    }
}

// finalize row_ptr, init cursor, compute invd
__global__ void scan3_kernel(int* __restrict__ rowptr, const int* __restrict__ blockSums,
                             int* __restrict__ cursor, const int* __restrict__ deg,
                             float* __restrict__ invd, int n) {
    int i = blockIdx.x * blockDim.x + threadIdx.x;
    if (i < n) {
        int v = rowptr[i] + blockSums[i >> 10];
        rowptr[i] = v;
        cursor[i] = v;
        invd[i] = 1.0f / fmaxf((float)deg[i], 1.0f);
    }
}

__global__ void fill_csr_kernel(const int* __restrict__ src, const int* __restrict__ dst,
                                int* __restrict__ cursor, int* __restrict__ csr_src, int n_edges) {
    int e = blockIdx.x * blockDim.x + threadIdx.x;
    if (e < n_edges) {
        int pos = atomicAdd(&cursor[dst[e]], 1);
        csr_src[pos] = src[e];
    }
}

// ---------------- gather aggregation: agg[d] = invd[d] * sum_{s in N(d)} h[s] ----------------
// 32 lanes per node, each lane owns a float4 chunk (32*4 = 128 feats).
__global__ void gather_agg_kernel(const float* __restrict__ h, const int* __restrict__ csr_src,
                                  const int* __restrict__ rowptr, const int* __restrict__ deg,
                                  const float* __restrict__ invd,
                                  float* __restrict__ agg, int n_nodes) {
    long long gid = (long long)blockIdx.x * blockDim.x + threadIdx.x;
    int node = (int)(gid >> 5);
    if (node >= n_nodes) return;
    int q = ((int)gid & 31) * 4;
    int start = rowptr[node];
    int end   = start + deg[node];
    float4 acc = make_float4(0.f, 0.f, 0.f, 0.f);
    for (int j = start; j < end; ++j) {
        int s = csr_src[j];
        float4 v = *reinterpret_cast<const float4*>(h + (size_t)s * HID + q);
        acc.x += v.x; acc.y += v.y; acc.z += v.z; acc.w += v.w;
    }
    float sc = invd[node];
    acc.x *= sc; acc.y *= sc; acc.z *= sc; acc.w *= sc;
    *reinterpret_cast<float4*>(agg + (size_t)node * HID + q) = acc;
}

// ---------------- fused dual-GEMM + epilogue ----------------
// out[i][:] = A[i]@Ws + Agg[i]@Wn + bias ; if HAS_MASK: where(mask, ., gh[g2[i]]) then relu
template<int NOUT, bool HAS_MASK>
__global__ __launch_bounds__(256) void gemm_fused(
    const float* __restrict__ A, const float* __restrict__ Agg,
    const float* __restrict__ Ws, const float* __restrict__ Wn,
    const float* __restrict__ bias,
    const float* __restrict__ gh, const int* __restrict__ g2,
    const int* __restrict__ mask,
    float* __restrict__ out, int n_rows)
{
    __shared__ float sA[64][33];
    __shared__ float sB[32][128];

    const int tid = threadIdx.x;
    const int tx  = tid & 15;
    const int tyy = tid >> 4;
    const int r0  = blockIdx.x * 64;

    float acc[4][8];
#pragma unroll
    for (int r = 0; r < 4; ++r)
#pragma unroll
        for (int c = 0; c < 8; ++c) acc[r][c] = 0.0f;

    for (int pass = 0; pass < 2; ++pass) {
        const float* __restrict__ Asrc = pass ? Agg : A;
        const float* __restrict__ W    = pass ? Wn  : Ws;
        for (int k0 = 0; k0 < 128; k0 += 32) {
            __syncthreads();
#pragma unroll
            for (int i = 0; i < 2; ++i) {
                int fid = tid + i * 256;
                int row = fid >> 3;
                int c4  = (fid & 7) * 4;
                int gr  = r0 + row;
                float4 v = make_float4(0.f, 0.f, 0.f, 0.f);
                if (gr < n_rows)
                    v = *reinterpret_cast<const float4*>(Asrc + (size_t)gr * HID + k0 + c4);
                sA[row][c4 + 0] = v.x;
                sA[row][c4 + 1] = v.y;
                sA[row][c4 + 2] = v.z;
                sA[row][c4 + 3] = v.w;
            }
#pragma unroll
            for (int i = 0; i < 4; ++i) {
                int fid = tid + i * 256;
                int row = fid >> 5;
                int col = (fid & 31) * 4;
                float4 v = make_float4(0.f, 0.f, 0.f, 0.f);
                if (col < NOUT)
                    v = *reinterpret_cast<const float4*>(W + (size_t)(k0 + row) * NOUT + col);
                *reinterpret_cast<float4*>(&sB[row][col]) = v;
            }
            __syncthreads();
#pragma unroll
            for (int k = 0; k < 32; ++k) {
                float a0 = sA[tyy * 4 + 0][k];
                float a1 = sA[tyy * 4 + 1][k];
                float a2 = sA[tyy * 4 + 2][k];
                float a3 = sA[tyy * 4 + 3][k];
                float4 blo = *reinterpret_cast<const float4*>(&sB[k][tx * 8]);
                float4 bhi = *reinterpret_cast<const float4*>(&sB[k][tx * 8 + 4]);
                acc[0][0] += a0 * blo.x; acc[0][1] += a0 * blo.y; acc[0][2] += a0 * blo.z; acc[0][3] += a0 * blo.w;
                acc[0][4] += a0 * bhi.x; acc[0][5] += a0 * bhi.y; acc[0][6] += a0 * bhi.z; acc[0][7] += a0 * bhi.w;
                acc[1][0] += a1 * blo.x; acc[1][1] += a1 * blo.y; acc[1][2] += a1 * blo.z; acc[1][3] += a1 * blo.w;
                acc[1][4] += a1 * bhi.x; acc[1][5] += a1 * bhi.y; acc[1][6] += a1 * bhi.z; acc[1][7] += a1 * bhi.w;
                acc[2][0] += a2 * blo.x; acc[2][1] += a2 * blo.y; acc[2][2] += a2 * blo.z; acc[2][3] += a2 * blo.w;
                acc[2][4] += a2 * bhi.x; acc[2][5] += a2 * bhi.y; acc[2][6] += a2 * bhi.z; acc[2][7] += a2 * bhi.w;
                acc[3][0] += a3 * blo.x; acc[3][1] += a3 * blo.y; acc[3][2] += a3 * blo.z; acc[3][3] += a3 * blo.w;
                acc[3][4] += a3 * bhi.x; acc[3][5] += a3 * bhi.y; acc[3][6] += a3 * bhi.z; acc[3][7] += a3 * bhi.w;
            }
        }
    }

#pragma unroll
    for (int rr = 0; rr < 4; ++rr) {
        int gr = r0 + tyy * 4 + rr;
        if (gr >= n_rows) continue;
        bool mk = true;
        const float* grow = nullptr;
        if (HAS_MASK) {
            mk = mask[gr] != 0;
            if (!mk) grow = gh + (size_t)g2[gr] * HID;
        }
#pragma unroll
        for (int h4 = 0; h4 < 2; ++h4) {
            int col = tx * 8 + h4 * 4;
            if (col >= NOUT) continue;
            float4 y;
            y.x = acc[rr][h4 * 4 + 0] + bias[col + 0];
            y.y = acc[rr][h4 * 4 + 1] + bias[col + 1];
            y.z = acc[rr][h4 * 4 + 2] + bias[col + 2];
            y.w = acc[rr][h4 * 4 + 3] + bias[col + 3];
            if (HAS_MASK) {
                if (!mk) {
                    y.x = grow[col + 0]; y.y = grow[col + 1];
                    y.z = grow[col + 2]; y.w = grow[col + 3];
                }
                y.x = fmaxf(y.x, 0.f); y.y = fmaxf(y.y, 0.f);
                y.z = fmaxf(y.z, 0.f); y.w = fmaxf(y.w, 0.f);
            }
            *reinterpret_cast<float4*>(out + (size_t)gr * NOUT + col) = y;
        }
    }
}

extern "C" void kernel_launch(void* const* d_in, const int* in_sizes, int n_in,
                              void* d_out, int out_size, void* d_ws, size_t ws_size,
                              hipStream_t stream) {
    const float* feat = (const float*)d_in[0];
    const float* gh   = (const float*)d_in[1];
    const float* gh2  = (const float*)d_in[2];
    const float* W1s  = (const float*)d_in[3];
    const float* W1n  = (const float*)d_in[4];
    const float* b1   = (const float*)d_in[5];
    const float* W2s  = (const float*)d_in[6];
    const float* W2n  = (const float*)d_in[7];
    const float* b2   = (const float*)d_in[8];
    const float* W3s  = (const float*)d_in[9];
    const float* W3n  = (const float*)d_in[10];
    const float* b3   = (const float*)d_in[11];
    const int* esrc   = (const int*)d_in[12];
    const int* edst   = (const int*)d_in[13];
    const int* g2     = (const int*)d_in[14];
    const int* mask   = (const int*)d_in[15];   // bool delivered as int32

    const int n_edges = in_sizes[12];
    const int n_nodes = in_sizes[14];
    float* out = (float*)d_out;

    // workspace layout (all 16B-aligned given n_nodes=100000, n_edges=1.6M)
    char* p = (char*)d_ws;
    int*   deg      = (int*)p;            p += (size_t)n_nodes * 4;
    int*   rowptr   = (int*)p;            p += (size_t)n_nodes * 4;
    int*   cursor   = (int*)p;            p += (size_t)n_nodes * 4;
    int*   bsums    = (int*)p;            p += 4096;
    float* invd     = (float*)p;          p += (size_t)n_nodes * 4;
    int*   csr_src  = (int*)p;            p += (size_t)n_edges * 4;
    float* agg      = (float*)p;          p += (size_t)n_nodes * HID * 4;
    float* h1       = (float*)p;          p += (size_t)n_nodes * HID * 4;
    float* h2       = (float*)p;          p += (size_t)n_nodes * HID * 4;

    const int nb_scan = (n_nodes + SCAN_ELEMS - 1) / SCAN_ELEMS;
    const int gblocks = (n_nodes + 63) / 64;
    const int agg_blocks = (int)(((long long)n_nodes * 32 + 255) / 256);

    // ---- CSR build (once per call, reused by all 3 layers) ----
    hipMemsetAsync(deg, 0, (size_t)n_nodes * sizeof(int), stream);
    deg_count_kernel<<<(n_edges + 255) / 256, 256, 0, stream>>>(edst, deg, n_edges);
    scan1_kernel<<<nb_scan, SCAN_BS, 0, stream>>>(deg, rowptr, bsums, n_nodes);
    scan2_kernel<<<1, 64, 0, stream>>>(bsums, nb_scan);
    scan3_kernel<<<(n_nodes + 255) / 256, 256, 0, stream>>>(rowptr, bsums, cursor, deg, invd, n_nodes);
    fill_csr_kernel<<<(n_edges + 255) / 256, 256, 0, stream>>>(esrc, edst, cursor, csr_src, n_edges);

    // ---- layer 1 ----
    gather_agg_kernel<<<agg_blocks, 256, 0, stream>>>(feat, csr_src, rowptr, deg, invd, agg, n_nodes);
    gemm_fused<128, true><<<gblocks, 256, 0, stream>>>(feat, agg, W1s, W1n, b1, gh, g2, mask, h1, n_nodes);

    // ---- layer 2 ----
    gather_agg_kernel<<<agg_blocks, 256, 0, stream>>>(h1, csr_src, rowptr, deg, invd, agg, n_nodes);
    gemm_fused<128, true><<<gblocks, 256, 0, stream>>>(h1, agg, W2s, W2n, b2, gh2, g2, mask, h2, n_nodes);

    // ---- layer 3 ----
    gather_agg_kernel<<<agg_blocks, 256, 0, stream>>>(h2, csr_src, rowptr, deg, invd, agg, n_nodes);
    gemm_fused<40, false><<<gblocks, 256, 0, stream>>>(h2, agg, W3s, W3n, b3, nullptr, nullptr, nullptr, out, n_nodes);
}

// Round 4
// 1088.965 us; speedup vs baseline: 8.1977x; 1.1675x over previous
//
#include <hip/hip_runtime.h>

#define HID 128

typedef __bf16 bf16x8 __attribute__((ext_vector_type(8)));
typedef float  f32x4  __attribute__((ext_vector_type(4)));

__device__ __forceinline__ unsigned f2b(float x) {           // fp32 -> bf16 bits, RNE
    unsigned u = __float_as_uint(x);
    return (u + 0x7fffu + ((u >> 16) & 1u)) >> 16;
}
__device__ __forceinline__ float b2f(unsigned b) {           // bf16 bits -> fp32
    return __uint_as_float(b << 16);
}

// ---------------- CSR build ----------------
__global__ void deg_count_kernel(const int* __restrict__ dst, int* __restrict__ deg, int n_edges) {
    int e = blockIdx.x * blockDim.x + threadIdx.x;
    if (e < n_edges) atomicAdd(&deg[dst[e]], 1);
}

#define SCAN_BS 256
#define SCAN_ELEMS 1024  // 4 per thread

__global__ void scan1_kernel(const int* __restrict__ deg, int* __restrict__ excl,
                             int* __restrict__ blockSums, int n) {
    __shared__ int s[SCAN_BS];
    int base = blockIdx.x * SCAN_ELEMS + threadIdx.x * 4;
    int v[4]; int t = 0;
#pragma unroll
    for (int i = 0; i < 4; ++i) { int idx = base + i; v[i] = (idx < n) ? deg[idx] : 0; t += v[i]; }
    s[threadIdx.x] = t;
    __syncthreads();
    for (int off = 1; off < SCAN_BS; off <<= 1) {
        int x = (threadIdx.x >= off) ? s[threadIdx.x - off] : 0;
        __syncthreads();
        s[threadIdx.x] += x;
        __syncthreads();
    }
    int run = s[threadIdx.x] - t;
#pragma unroll
    for (int i = 0; i < 4; ++i) { int idx = base + i; if (idx < n) excl[idx] = run; run += v[i]; }
    if (threadIdx.x == SCAN_BS - 1) blockSums[blockIdx.x] = s[SCAN_BS - 1];
}

// single-block exclusive scan of blockSums (nb <= 256)
__global__ void scan2_kernel(int* __restrict__ bsums, int nb) {
    __shared__ int s[256];
    int i = threadIdx.x;
    int v = (i < nb) ? bsums[i] : 0;
    s[i] = v;
    __syncthreads();
    for (int off = 1; off < 256; off <<= 1) {
        int x = (i >= off) ? s[i - off] : 0;
        __syncthreads();
        s[i] += x;
        __syncthreads();
    }
    if (i < nb) bsums[i] = s[i] - v;
}

__global__ void scan3_kernel(int* __restrict__ rowptr, const int* __restrict__ blockSums,
                             int* __restrict__ cursor, const int* __restrict__ deg,
                             float* __restrict__ invd, int n) {
    int i = blockIdx.x * blockDim.x + threadIdx.x;
    if (i < n) {
        int v = rowptr[i] + blockSums[i >> 10];
        rowptr[i] = v;
        cursor[i] = v;
        invd[i] = 1.0f / fmaxf((float)deg[i], 1.0f);
    }
}

__global__ void fill_csr_kernel(const int* __restrict__ src, const int* __restrict__ dst,
                                int* __restrict__ cursor, int* __restrict__ csr_src, int n_edges) {
    int e = blockIdx.x * blockDim.x + threadIdx.x;
    if (e < n_edges) {
        int pos = atomicAdd(&cursor[dst[e]], 1);
        csr_src[pos] = src[e];
    }
}

// ---------------- fp32 -> bf16 feature convert ----------------
__global__ void cvt_bf16_kernel(const float* __restrict__ in, unsigned short* __restrict__ out, int total4) {
    int i = blockIdx.x * blockDim.x + threadIdx.x;
    if (i >= total4) return;
    float4 v = reinterpret_cast<const float4*>(in)[i];
    uint2 o;
    o.x = f2b(v.x) | (f2b(v.y) << 16);
    o.y = f2b(v.z) | (f2b(v.w) << 16);
    reinterpret_cast<uint2*>(out)[i] = o;
}

// ---------------- weight prep: Wt[n][k] bf16, k = [Ws rows | Wn rows] ----------------
template<int NOUT>
__global__ void build_wt_kernel(const float* __restrict__ Ws, const float* __restrict__ Wn,
                                unsigned short* __restrict__ wt) {
    int idx = blockIdx.x * blockDim.x + threadIdx.x;   // n*256 + k
    int n = idx >> 8;
    int k = idx & 255;
    float v = 0.f;
    if (n < NOUT) v = (k < 128) ? Ws[k * NOUT + n] : Wn[(k - 128) * NOUT + n];
    wt[idx] = (unsigned short)f2b(v);
}

// ---------------- gather aggregation (bf16): agg[d] = invd[d] * sum h[s] ----------------
// 16 lanes per node, lane owns 8 bf16 (16 B).
__global__ void gather_agg_kernel(const unsigned short* __restrict__ h, const int* __restrict__ csr_src,
                                  const int* __restrict__ rowptr, const int* __restrict__ deg,
                                  const float* __restrict__ invd,
                                  unsigned short* __restrict__ agg, int n_nodes) {
    long long gid = (long long)blockIdx.x * blockDim.x + threadIdx.x;
    int node = (int)(gid >> 4);
    if (node >= n_nodes) return;
    int q = ((int)gid & 15) * 8;
    int start = rowptr[node];
    int end   = start + deg[node];
    float acc[8];
#pragma unroll
    for (int i = 0; i < 8; ++i) acc[i] = 0.f;
    for (int j = start; j < end; ++j) {
        int s = csr_src[j];
        uint4 v = *reinterpret_cast<const uint4*>(h + (size_t)s * HID + q);
        acc[0] += b2f(v.x & 0xffffu); acc[1] += b2f(v.x >> 16);
        acc[2] += b2f(v.y & 0xffffu); acc[3] += b2f(v.y >> 16);
        acc[4] += b2f(v.z & 0xffffu); acc[5] += b2f(v.z >> 16);
        acc[6] += b2f(v.w & 0xffffu); acc[7] += b2f(v.w >> 16);
    }
    float sc = invd[node];
    uint4 o;
    o.x = f2b(acc[0] * sc) | (f2b(acc[1] * sc) << 16);
    o.y = f2b(acc[2] * sc) | (f2b(acc[3] * sc) << 16);
    o.z = f2b(acc[4] * sc) | (f2b(acc[5] * sc) << 16);
    o.w = f2b(acc[6] * sc) | (f2b(acc[7] * sc) << 16);
    *reinterpret_cast<uint4*>(agg + (size_t)node * HID + q) = o;
}

// ---------------- MFMA dual-GEMM + epilogue ----------------
// out[m][n] = sum_k [A|Agg][m][k] * Wt[n][k] + bias[n]; optional mask-select + relu.
// Block = 256 thr = 4 waves; wave covers 32 rows (2 m-tiles of 16); NT n-tiles of 16.
template<int NOUT, bool HAS_MASK, bool OUT_BF16>
__global__ __launch_bounds__(256) void gemm_mfma(
    const unsigned short* __restrict__ Aself, const unsigned short* __restrict__ Aagg,
    const unsigned short* __restrict__ Wt,    // [NT*16][256] bf16
    const float* __restrict__ bias,
    const float* __restrict__ gh, const int* __restrict__ g2,
    const int* __restrict__ mask,
    void* __restrict__ outv, int n_rows)
{
    constexpr int NT = (NOUT + 15) / 16;
    const int lane = threadIdx.x & 63;
    const int wave = threadIdx.x >> 6;
    const int m16  = lane & 15;
    const int quad = lane >> 4;
    const int rowBase = blockIdx.x * 128 + wave * 32;

    f32x4 acc[2][NT];
#pragma unroll
    for (int mt = 0; mt < 2; ++mt)
#pragma unroll
        for (int t = 0; t < NT; ++t) acc[mt][t] = (f32x4){0.f, 0.f, 0.f, 0.f};

    const int koffq = quad * 8;
#pragma unroll
    for (int s = 0; s < 8; ++s) {
        const unsigned short* Ab = (s < 4) ? Aself : Aagg;
        const int ka = (s & 3) * 32 + koffq;
        bf16x8 a0 = *reinterpret_cast<const bf16x8*>(Ab + (size_t)(rowBase + m16) * HID + ka);
        bf16x8 a1 = *reinterpret_cast<const bf16x8*>(Ab + (size_t)(rowBase + 16 + m16) * HID + ka);
        const int kb = s * 32 + koffq;
#pragma unroll
        for (int t = 0; t < NT; ++t) {
            bf16x8 b = *reinterpret_cast<const bf16x8*>(Wt + (size_t)(t * 16 + m16) * 256 + kb);
            acc[0][t] = __builtin_amdgcn_mfma_f32_16x16x32_bf16(a0, b, acc[0][t], 0, 0, 0);
            acc[1][t] = __builtin_amdgcn_mfma_f32_16x16x32_bf16(a1, b, acc[1][t], 0, 0, 0);
        }
    }

#pragma unroll
    for (int mt = 0; mt < 2; ++mt) {
#pragma unroll
        for (int r = 0; r < 4; ++r) {
            int row = rowBase + mt * 16 + quad * 4 + r;
            if (row >= n_rows) continue;
            bool mk = true;
            const float* grow = nullptr;
            if (HAS_MASK) {
                mk = mask[row] != 0;
                if (!mk) grow = gh + (size_t)g2[row] * HID;
            }
#pragma unroll
            for (int t = 0; t < NT; ++t) {
                int col = t * 16 + m16;
                if (col >= NOUT) continue;
                float v = acc[mt][t][r] + bias[col];
                if (HAS_MASK) {
                    if (!mk) v = grow[col];
                    v = fmaxf(v, 0.f);
                }
                if (OUT_BF16)
                    ((unsigned short*)outv)[(size_t)row * NOUT + col] = (unsigned short)f2b(v);
                else
                    ((float*)outv)[(size_t)row * NOUT + col] = v;
            }
        }
    }
}

extern "C" void kernel_launch(void* const* d_in, const int* in_sizes, int n_in,
                              void* d_out, int out_size, void* d_ws, size_t ws_size,
                              hipStream_t stream) {
    const float* feat = (const float*)d_in[0];
    const float* gh   = (const float*)d_in[1];
    const float* gh2  = (const float*)d_in[2];
    const float* W1s  = (const float*)d_in[3];
    const float* W1n  = (const float*)d_in[4];
    const float* b1   = (const float*)d_in[5];
    const float* W2s  = (const float*)d_in[6];
    const float* W2n  = (const float*)d_in[7];
    const float* b2   = (const float*)d_in[8];
    const float* W3s  = (const float*)d_in[9];
    const float* W3n  = (const float*)d_in[10];
    const float* b3   = (const float*)d_in[11];
    const int* esrc   = (const int*)d_in[12];
    const int* edst   = (const int*)d_in[13];
    const int* g2     = (const int*)d_in[14];
    const int* mask   = (const int*)d_in[15];   // bool delivered as int32

    const int n_edges = in_sizes[12];
    const int n_nodes = in_sizes[14];
    const int n_pad   = ((n_nodes + 127) / 128) * 128;   // GEMM reads up to n_pad rows
    float* out = (float*)d_out;

    // workspace layout (16B aligned throughout)
    char* p = (char*)d_ws;
    int*   deg      = (int*)p;              p += (size_t)n_nodes * 4;
    int*   rowptr   = (int*)p;              p += (size_t)n_nodes * 4;
    int*   cursor   = (int*)p;              p += (size_t)n_nodes * 4;
    int*   bsums    = (int*)p;              p += 4096;
    float* invd     = (float*)p;            p += (size_t)n_nodes * 4;
    int*   csr_src  = (int*)p;              p += (size_t)n_edges * 4;
    unsigned short* hb0  = (unsigned short*)p; p += (size_t)n_pad * HID * 2;
    unsigned short* aggb = (unsigned short*)p; p += (size_t)n_pad * HID * 2;
    unsigned short* h1b  = (unsigned short*)p; p += (size_t)n_pad * HID * 2;
    unsigned short* h2b  = (unsigned short*)p; p += (size_t)n_pad * HID * 2;
    unsigned short* wt1  = (unsigned short*)p; p += (size_t)128 * 256 * 2;
    unsigned short* wt2  = (unsigned short*)p; p += (size_t)128 * 256 * 2;
    unsigned short* wt3  = (unsigned short*)p; p += (size_t)48  * 256 * 2;

    const int nb_scan = (n_nodes + SCAN_ELEMS - 1) / SCAN_ELEMS;
    const int gemm_blocks = (n_nodes + 127) / 128;
    const int agg_blocks  = (int)(((long long)n_nodes * 16 + 255) / 256);
    const int cvt4 = n_nodes * HID / 4;

    // ---- CSR build ----
    hipMemsetAsync(deg, 0, (size_t)n_nodes * sizeof(int), stream);
    deg_count_kernel<<<(n_edges + 255) / 256, 256, 0, stream>>>(edst, deg, n_edges);
    scan1_kernel<<<nb_scan, SCAN_BS, 0, stream>>>(deg, rowptr, bsums, n_nodes);
    scan2_kernel<<<1, 256, 0, stream>>>(bsums, nb_scan);
    scan3_kernel<<<(n_nodes + 255) / 256, 256, 0, stream>>>(rowptr, bsums, cursor, deg, invd, n_nodes);
    fill_csr_kernel<<<(n_edges + 255) / 256, 256, 0, stream>>>(esrc, edst, cursor, csr_src, n_edges);

    // ---- prep: bf16 features + transposed bf16 weights ----
    cvt_bf16_kernel<<<(cvt4 + 255) / 256, 256, 0, stream>>>(feat, hb0, cvt4);
    build_wt_kernel<128><<<128, 256, 0, stream>>>(W1s, W1n, wt1);
    build_wt_kernel<128><<<128, 256, 0, stream>>>(W2s, W2n, wt2);
    build_wt_kernel<40><<<48, 256, 0, stream>>>(W3s, W3n, wt3);

    // ---- layer 1 ----
    gather_agg_kernel<<<agg_blocks, 256, 0, stream>>>(hb0, csr_src, rowptr, deg, invd, aggb, n_nodes);
    gemm_mfma<128, true, true><<<gemm_blocks, 256, 0, stream>>>(hb0, aggb, wt1, b1, gh, g2, mask, h1b, n_nodes);

    // ---- layer 2 ----
    gather_agg_kernel<<<agg_blocks, 256, 0, stream>>>(h1b, csr_src, rowptr, deg, invd, aggb, n_nodes);
    gemm_mfma<128, true, true><<<gemm_blocks, 256, 0, stream>>>(h1b, aggb, wt2, b2, gh2, g2, mask, h2b, n_nodes);

    // ---- layer 3 (fp32 out, 40 cols) ----
    gather_agg_kernel<<<agg_blocks, 256, 0, stream>>>(h2b, csr_src, rowptr, deg, invd, aggb, n_nodes);
    gemm_mfma<40, false, false><<<gemm_blocks, 256, 0, stream>>>(h2b, aggb, wt3, b3, nullptr, nullptr, nullptr, out, n_nodes);
}

// Round 5
// 1037.564 us; speedup vs baseline: 8.6038x; 1.0495x over previous
//
#include <hip/hip_runtime.h>

#define HID 128

typedef __bf16 bf16x8 __attribute__((ext_vector_type(8)));
typedef float  f32x4  __attribute__((ext_vector_type(4)));

__device__ __forceinline__ unsigned f2b(float x) {           // fp32 -> bf16 bits, RNE
    unsigned u = __float_as_uint(x);
    return (u + 0x7fffu + ((u >> 16) & 1u)) >> 16;
}
__device__ __forceinline__ float b2f(unsigned b) {           // bf16 bits -> fp32
    return __uint_as_float(b << 16);
}

// ---------------- CSR build ----------------
__global__ void deg_count_kernel(const int* __restrict__ dst, int* __restrict__ deg, int n_edges) {
    int e = blockIdx.x * blockDim.x + threadIdx.x;
    if (e < n_edges) atomicAdd(&deg[dst[e]], 1);
}

#define SCAN_BS 256
#define SCAN_ELEMS 1024  // 4 per thread

__global__ void scan1_kernel(const int* __restrict__ deg, int* __restrict__ excl,
                             int* __restrict__ blockSums, int n) {
    __shared__ int s[SCAN_BS];
    int base = blockIdx.x * SCAN_ELEMS + threadIdx.x * 4;
    int v[4]; int t = 0;
#pragma unroll
    for (int i = 0; i < 4; ++i) { int idx = base + i; v[i] = (idx < n) ? deg[idx] : 0; t += v[i]; }
    s[threadIdx.x] = t;
    __syncthreads();
    for (int off = 1; off < SCAN_BS; off <<= 1) {
        int x = (threadIdx.x >= off) ? s[threadIdx.x - off] : 0;
        __syncthreads();
        s[threadIdx.x] += x;
        __syncthreads();
    }
    int run = s[threadIdx.x] - t;
#pragma unroll
    for (int i = 0; i < 4; ++i) { int idx = base + i; if (idx < n) excl[idx] = run; run += v[i]; }
    if (threadIdx.x == SCAN_BS - 1) blockSums[blockIdx.x] = s[SCAN_BS - 1];
}

// single-block exclusive scan of blockSums (nb <= 256)
__global__ void scan2_kernel(int* __restrict__ bsums, int nb) {
    __shared__ int s[256];
    int i = threadIdx.x;
    int v = (i < nb) ? bsums[i] : 0;
    s[i] = v;
    __syncthreads();
    for (int off = 1; off < 256; off <<= 1) {
        int x = (i >= off) ? s[i - off] : 0;
        __syncthreads();
        s[i] += x;
        __syncthreads();
    }
    if (i < nb) bsums[i] = s[i] - v;
}

__global__ void scan3_kernel(int* __restrict__ rowptr, const int* __restrict__ blockSums,
                             int* __restrict__ cursor, const int* __restrict__ deg,
                             float* __restrict__ invd, int n) {
    int i = blockIdx.x * blockDim.x + threadIdx.x;
    if (i < n) {
        int v = rowptr[i] + blockSums[i >> 10];
        rowptr[i] = v;
        cursor[i] = v;
        invd[i] = 1.0f / fmaxf((float)deg[i], 1.0f);
    }
}

__global__ void fill_csr_kernel(const int* __restrict__ src, const int* __restrict__ dst,
                                int* __restrict__ cursor, int* __restrict__ csr_src, int n_edges) {
    int e = blockIdx.x * blockDim.x + threadIdx.x;
    if (e < n_edges) {
        int pos = atomicAdd(&cursor[dst[e]], 1);
        csr_src[pos] = src[e];
    }
}
// after fill_csr, cursor[i] == rowptr[i] + deg[i]  -> reused as row-end pointer

// ---------------- fp32 -> bf16 feature convert ----------------
__global__ void cvt_bf16_kernel(const float* __restrict__ in, unsigned short* __restrict__ out, int total4) {
    int i = blockIdx.x * blockDim.x + threadIdx.x;
    if (i >= total4) return;
    float4 v = reinterpret_cast<const float4*>(in)[i];
    uint2 o;
    o.x = f2b(v.x) | (f2b(v.y) << 16);
    o.y = f2b(v.z) | (f2b(v.w) << 16);
    reinterpret_cast<uint2*>(out)[i] = o;
}

// ---------------- weight prep: Wt[n][k] bf16, k = [Ws rows | Wn rows] ----------------
template<int NOUT>
__global__ void build_wt_kernel(const float* __restrict__ Ws, const float* __restrict__ Wn,
                                unsigned short* __restrict__ wt) {
    int idx = blockIdx.x * blockDim.x + threadIdx.x;   // n*256 + k
    int n = idx >> 8;
    int k = idx & 255;
    float v = 0.f;
    if (n < NOUT) v = (k < 128) ? Ws[k * NOUT + n] : Wn[(k - 128) * NOUT + n];
    wt[idx] = (unsigned short)f2b(v);
}

// ---------------- gather aggregation (bf16): agg[d] = invd[d] * sum h[s] ----------------
// ONE WAVE PER NODE: 4 edge slots (grp) x 16 lanes x 16 B. Unroll 2 -> up to 8
// independent row loads in flight per wave; no inter-node divergence.
__global__ void gather_agg_kernel(const unsigned short* __restrict__ h, const int* __restrict__ csr_src,
                                  const int* __restrict__ rowptr, const int* __restrict__ rowend,
                                  const float* __restrict__ invd,
                                  unsigned short* __restrict__ agg, int n_nodes) {
    int node = blockIdx.x * 4 + (threadIdx.x >> 6);
    if (node >= n_nodes) return;
    const int lane = threadIdx.x & 63;
    const int grp  = lane >> 4;        // edge slot 0..3
    const int q    = (lane & 15) * 8;  // bf16 offset within row
    const int start = rowptr[node];
    const int end   = rowend[node];

    float acc[8];
#pragma unroll
    for (int i = 0; i < 8; ++i) acc[i] = 0.f;

    int j = start + grp;
    for (; j + 4 < end; j += 8) {
        int s0 = csr_src[j];
        int s1 = csr_src[j + 4];
        uint4 v0 = *reinterpret_cast<const uint4*>(h + (size_t)s0 * HID + q);
        uint4 v1 = *reinterpret_cast<const uint4*>(h + (size_t)s1 * HID + q);
        acc[0] += b2f(v0.x & 0xffffu); acc[1] += b2f(v0.x >> 16);
        acc[2] += b2f(v0.y & 0xffffu); acc[3] += b2f(v0.y >> 16);
        acc[4] += b2f(v0.z & 0xffffu); acc[5] += b2f(v0.z >> 16);
        acc[6] += b2f(v0.w & 0xffffu); acc[7] += b2f(v0.w >> 16);
        acc[0] += b2f(v1.x & 0xffffu); acc[1] += b2f(v1.x >> 16);
        acc[2] += b2f(v1.y & 0xffffu); acc[3] += b2f(v1.y >> 16);
        acc[4] += b2f(v1.z & 0xffffu); acc[5] += b2f(v1.z >> 16);
        acc[6] += b2f(v1.w & 0xffffu); acc[7] += b2f(v1.w >> 16);
    }
    if (j < end) {
        int s0 = csr_src[j];
        uint4 v0 = *reinterpret_cast<const uint4*>(h + (size_t)s0 * HID + q);
        acc[0] += b2f(v0.x & 0xffffu); acc[1] += b2f(v0.x >> 16);
        acc[2] += b2f(v0.y & 0xffffu); acc[3] += b2f(v0.y >> 16);
        acc[4] += b2f(v0.z & 0xffffu); acc[5] += b2f(v0.z >> 16);
        acc[6] += b2f(v0.w & 0xffffu); acc[7] += b2f(v0.w >> 16);
    }

    // reduce across the 4 edge slots (lanes differing in bits 4,5)
#pragma unroll
    for (int i = 0; i < 8; ++i) {
        acc[i] += __shfl_xor(acc[i], 16, 64);
        acc[i] += __shfl_xor(acc[i], 32, 64);
    }

    if (grp == 0) {
        float sc = invd[node];
        uint4 o;
        o.x = f2b(acc[0] * sc) | (f2b(acc[1] * sc) << 16);
        o.y = f2b(acc[2] * sc) | (f2b(acc[3] * sc) << 16);
        o.z = f2b(acc[4] * sc) | (f2b(acc[5] * sc) << 16);
        o.w = f2b(acc[6] * sc) | (f2b(acc[7] * sc) << 16);
        *reinterpret_cast<uint4*>(agg + (size_t)node * HID + q) = o;
    }
}

// ---------------- MFMA dual-GEMM + epilogue ----------------
template<int NOUT, bool HAS_MASK, bool OUT_BF16>
__global__ __launch_bounds__(256) void gemm_mfma(
    const unsigned short* __restrict__ Aself, const unsigned short* __restrict__ Aagg,
    const unsigned short* __restrict__ Wt,    // [NT*16][256] bf16
    const float* __restrict__ bias,
    const float* __restrict__ gh, const int* __restrict__ g2,
    const int* __restrict__ mask,
    void* __restrict__ outv, int n_rows)
{
    constexpr int NT = (NOUT + 15) / 16;
    const int lane = threadIdx.x & 63;
    const int wave = threadIdx.x >> 6;
    const int m16  = lane & 15;
    const int quad = lane >> 4;
    const int rowBase = blockIdx.x * 128 + wave * 32;

    f32x4 acc[2][NT];
#pragma unroll
    for (int mt = 0; mt < 2; ++mt)
#pragma unroll
        for (int t = 0; t < NT; ++t) acc[mt][t] = (f32x4){0.f, 0.f, 0.f, 0.f};

    const int koffq = quad * 8;
#pragma unroll
    for (int s = 0; s < 8; ++s) {
        const unsigned short* Ab = (s < 4) ? Aself : Aagg;
        const int ka = (s & 3) * 32 + koffq;
        bf16x8 a0 = *reinterpret_cast<const bf16x8*>(Ab + (size_t)(rowBase + m16) * HID + ka);
        bf16x8 a1 = *reinterpret_cast<const bf16x8*>(Ab + (size_t)(rowBase + 16 + m16) * HID + ka);
        const int kb = s * 32 + koffq;
#pragma unroll
        for (int t = 0; t < NT; ++t) {
            bf16x8 b = *reinterpret_cast<const bf16x8*>(Wt + (size_t)(t * 16 + m16) * 256 + kb);
            acc[0][t] = __builtin_amdgcn_mfma_f32_16x16x32_bf16(a0, b, acc[0][t], 0, 0, 0);
            acc[1][t] = __builtin_amdgcn_mfma_f32_16x16x32_bf16(a1, b, acc[1][t], 0, 0, 0);
        }
    }

#pragma unroll
    for (int mt = 0; mt < 2; ++mt) {
#pragma unroll
        for (int r = 0; r < 4; ++r) {
            int row = rowBase + mt * 16 + quad * 4 + r;
            if (row >= n_rows) continue;
            bool mk = true;
            const float* grow = nullptr;
            if (HAS_MASK) {
                mk = mask[row] != 0;
                if (!mk) grow = gh + (size_t)g2[row] * HID;
            }
#pragma unroll
            for (int t = 0; t < NT; ++t) {
                int col = t * 16 + m16;
                if (col >= NOUT) continue;
                float v = acc[mt][t][r] + bias[col];
                if (HAS_MASK) {
                    if (!mk) v = grow[col];
                    v = fmaxf(v, 0.f);
                }
                if (OUT_BF16)
                    ((unsigned short*)outv)[(size_t)row * NOUT + col] = (unsigned short)f2b(v);
                else
                    ((float*)outv)[(size_t)row * NOUT + col] = v;
            }
        }
    }
}

extern "C" void kernel_launch(void* const* d_in, const int* in_sizes, int n_in,
                              void* d_out, int out_size, void* d_ws, size_t ws_size,
                              hipStream_t stream) {
    const float* feat = (const float*)d_in[0];
    const float* gh   = (const float*)d_in[1];
    const float* gh2  = (const float*)d_in[2];
    const float* W1s  = (const float*)d_in[3];
    const float* W1n  = (const float*)d_in[4];
    const float* b1   = (const float*)d_in[5];
    const float* W2s  = (const float*)d_in[6];
    const float* W2n  = (const float*)d_in[7];
    const float* b2   = (const float*)d_in[8];
    const float* W3s  = (const float*)d_in[9];
    const float* W3n  = (const float*)d_in[10];
    const float* b3   = (const float*)d_in[11];
    const int* esrc   = (const int*)d_in[12];
    const int* edst   = (const int*)d_in[13];
    const int* g2     = (const int*)d_in[14];
    const int* mask   = (const int*)d_in[15];   // bool delivered as int32

    const int n_edges = in_sizes[12];
    const int n_nodes = in_sizes[14];
    const int n_pad   = ((n_nodes + 127) / 128) * 128;
    float* out = (float*)d_out;

    // workspace layout (16B aligned throughout)
    char* p = (char*)d_ws;
    int*   deg      = (int*)p;              p += (size_t)n_nodes * 4;
    int*   rowptr   = (int*)p;              p += (size_t)n_nodes * 4;
    int*   cursor   = (int*)p;              p += (size_t)n_nodes * 4;
    int*   bsums    = (int*)p;              p += 4096;
    float* invd     = (float*)p;            p += (size_t)n_nodes * 4;
    int*   csr_src  = (int*)p;              p += (size_t)n_edges * 4;
    unsigned short* hb0  = (unsigned short*)p; p += (size_t)n_pad * HID * 2;
    unsigned short* aggb = (unsigned short*)p; p += (size_t)n_pad * HID * 2;
    unsigned short* h1b  = (unsigned short*)p; p += (size_t)n_pad * HID * 2;
    unsigned short* h2b  = (unsigned short*)p; p += (size_t)n_pad * HID * 2;
    unsigned short* wt1  = (unsigned short*)p; p += (size_t)128 * 256 * 2;
    unsigned short* wt2  = (unsigned short*)p; p += (size_t)128 * 256 * 2;
    unsigned short* wt3  = (unsigned short*)p; p += (size_t)48  * 256 * 2;

    const int nb_scan = (n_nodes + SCAN_ELEMS - 1) / SCAN_ELEMS;
    const int gemm_blocks = (n_nodes + 127) / 128;
    const int agg_blocks  = (n_nodes + 3) / 4;    // 4 waves/block, 1 wave per node
    const int cvt4 = n_nodes * HID / 4;

    // ---- CSR build ----
    hipMemsetAsync(deg, 0, (size_t)n_nodes * sizeof(int), stream);
    deg_count_kernel<<<(n_edges + 255) / 256, 256, 0, stream>>>(edst, deg, n_edges);
    scan1_kernel<<<nb_scan, SCAN_BS, 0, stream>>>(deg, rowptr, bsums, n_nodes);
    scan2_kernel<<<1, 256, 0, stream>>>(bsums, nb_scan);
    scan3_kernel<<<(n_nodes + 255) / 256, 256, 0, stream>>>(rowptr, bsums, cursor, deg, invd, n_nodes);
    fill_csr_kernel<<<(n_edges + 255) / 256, 256, 0, stream>>>(esrc, edst, cursor, csr_src, n_edges);

    // ---- prep: bf16 features + transposed bf16 weights ----
    cvt_bf16_kernel<<<(cvt4 + 255) / 256, 256, 0, stream>>>(feat, hb0, cvt4);
    build_wt_kernel<128><<<128, 256, 0, stream>>>(W1s, W1n, wt1);
    build_wt_kernel<128><<<128, 256, 0, stream>>>(W2s, W2n, wt2);
    build_wt_kernel<40><<<48, 256, 0, stream>>>(W3s, W3n, wt3);

    // ---- layer 1 ----
    gather_agg_kernel<<<agg_blocks, 256, 0, stream>>>(hb0, csr_src, rowptr, cursor, invd, aggb, n_nodes);
    gemm_mfma<128, true, true><<<gemm_blocks, 256, 0, stream>>>(hb0, aggb, wt1, b1, gh, g2, mask, h1b, n_nodes);

    // ---- layer 2 ----
    gather_agg_kernel<<<agg_blocks, 256, 0, stream>>>(h1b, csr_src, rowptr, cursor, invd, aggb, n_nodes);
    gemm_mfma<128, true, true><<<gemm_blocks, 256, 0, stream>>>(h1b, aggb, wt2, b2, gh2, g2, mask, h2b, n_nodes);

    // ---- layer 3 (fp32 out, 40 cols) ----
    gather_agg_kernel<<<agg_blocks, 256, 0, stream>>>(h2b, csr_src, rowptr, cursor, invd, aggb, n_nodes);
    gemm_mfma<40, false, false><<<gemm_blocks, 256, 0, stream>>>(h2b, aggb, wt3, b3, nullptr, nullptr, nullptr, out, n_nodes);
}